// Round 1
// baseline (436.818 us; speedup 1.0000x reference)
//
#include <hip/hip_runtime.h>
#include <math.h>

// Problem constants (B, S, H) = (32, 2048, 1024)
constexpr int B = 32;
constexpr int S = 2048;
constexpr int H = 1024;

// ---------------------------------------------------------------------------
// Kernel 1: u_e[d] = sum_h v[h] * W_attn[h, H + d]      (W_attn is H x 2H)
// One thread per d; for fixed h consecutive threads read consecutive addrs
// (coalesced). 4 MB total read — trivial.
// ---------------------------------------------------------------------------
__global__ __launch_bounds__(256) void ue_kernel(const float* __restrict__ W,
                                                 const float* __restrict__ v,
                                                 float* __restrict__ ue) {
    const int d = blockIdx.x * 256 + threadIdx.x;   // 0..H-1
    float acc = 0.f;
    #pragma unroll 8
    for (int h = 0; h < H; ++h) {
        acc = fmaf(v[h], W[(size_t)h * (2 * H) + H + d], acc);
    }
    ue[d] = acc;
}

// ---------------------------------------------------------------------------
// Kernel 2: energy[row] = dot(enc[row, :], ue)   for row in [0, B*S)
// One wave (64 lanes) per row; each lane does 4x float4 loads (row = 4 KB).
// ue (4 KB) stays resident in L1. This kernel reads the full 268 MB encoder
// tensor once — the memory-bound floor of the whole op.
// ---------------------------------------------------------------------------
__global__ __launch_bounds__(256) void energy_kernel(const float* __restrict__ enc,
                                                     const float* __restrict__ ue,
                                                     float* __restrict__ energy) {
    const int wave = threadIdx.x >> 6;              // 0..3
    const int lane = threadIdx.x & 63;
    const int row  = blockIdx.x * 4 + wave;         // 0..B*S-1

    const float4* __restrict__ erow = reinterpret_cast<const float4*>(enc) + (size_t)row * (H / 4);
    const float4* __restrict__ u4   = reinterpret_cast<const float4*>(ue);

    float acc = 0.f;
    #pragma unroll
    for (int it = 0; it < H / 4 / 64; ++it) {       // 4 iterations
        const int idx = it * 64 + lane;
        const float4 e = erow[idx];
        const float4 u = u4[idx];
        acc += e.x * u.x + e.y * u.y + e.z * u.z + e.w * u.w;
    }
    // 64-lane butterfly reduce
    #pragma unroll
    for (int off = 32; off > 0; off >>= 1)
        acc += __shfl_xor(acc, off, 64);
    if (lane == 0) energy[row] = acc;
}

// ---------------------------------------------------------------------------
// Kernel 3: out[b, s] = softmax_s(energy[b, :])   — one block per b.
// 256 threads x 8 elements each = 2048. Two-level (wave -> LDS) reductions.
// ---------------------------------------------------------------------------
__global__ __launch_bounds__(256) void softmax_kernel(const float* __restrict__ energy,
                                                      float* __restrict__ out) {
    const int b    = blockIdx.x;
    const int tid  = threadIdx.x;
    const int lane = tid & 63;
    const int wave = tid >> 6;

    const float* __restrict__ e = energy + (size_t)b * S;

    float vals[8];
    float m = -INFINITY;
    #pragma unroll
    for (int i = 0; i < 8; ++i) {
        vals[i] = e[tid + i * 256];
        m = fmaxf(m, vals[i]);
    }
    #pragma unroll
    for (int off = 32; off > 0; off >>= 1)
        m = fmaxf(m, __shfl_xor(m, off, 64));

    __shared__ float wred[4];
    if (lane == 0) wred[wave] = m;
    __syncthreads();
    m = fmaxf(fmaxf(wred[0], wred[1]), fmaxf(wred[2], wred[3]));
    __syncthreads();   // wred reused below

    float sum = 0.f;
    #pragma unroll
    for (int i = 0; i < 8; ++i) {
        vals[i] = expf(vals[i] - m);
        sum += vals[i];
    }
    #pragma unroll
    for (int off = 32; off > 0; off >>= 1)
        sum += __shfl_xor(sum, off, 64);
    if (lane == 0) wred[wave] = sum;
    __syncthreads();
    sum = wred[0] + wred[1] + wred[2] + wred[3];

    const float inv = 1.0f / sum;
    #pragma unroll
    for (int i = 0; i < 8; ++i)
        out[(size_t)b * S + tid + i * 256] = vals[i] * inv;
}

// ---------------------------------------------------------------------------
// Launch. Inputs: [0]=encoder_outputs (B,S,H) f32, [1]=rnn_hidden (unused —
// cancels in softmax), [2]=W_attn (H,2H) f32, [3]=b_attn (unused — cancels),
// [4]=v (H,) f32. Output: (B,1,S) f32.
// Workspace layout: [0, 4KB) = u_e, [4KB, 4KB+256KB) = energy.
// ---------------------------------------------------------------------------
extern "C" void kernel_launch(void* const* d_in, const int* in_sizes, int n_in,
                              void* d_out, int out_size, void* d_ws, size_t ws_size,
                              hipStream_t stream) {
    const float* enc = (const float*)d_in[0];
    const float* W   = (const float*)d_in[2];
    const float* v   = (const float*)d_in[4];
    float* out       = (float*)d_out;

    float* ue     = (float*)d_ws;                       // H floats = 4 KB
    float* energy = (float*)((char*)d_ws + H * sizeof(float)); // B*S floats = 256 KB

    ue_kernel<<<H / 256, 256, 0, stream>>>(W, v, ue);
    energy_kernel<<<(B * S) / 4, 256, 0, stream>>>(enc, ue, energy);
    softmax_kernel<<<B, 256, 0, stream>>>(energy, out);
}

// Round 2
// 365.114 us; speedup vs baseline: 1.1964x; 1.1964x over previous
//
#include <hip/hip_runtime.h>
#include <math.h>

// Problem constants (B, S, H) = (32, 2048, 1024)
constexpr int B = 32;
constexpr int S = 2048;
constexpr int H = 1024;
constexpr int NSEG = 32;           // h-segments for the u_e partial reduction

// ---------------------------------------------------------------------------
// Softmax-shift cancellation: energy[b,s] = const(b) + enc[b,s,:]·u_e where
// u_e[d] = sum_h v[h]*W_attn[h, H+d]. rnn_hidden / W_h / b_attn cancel.
// ---------------------------------------------------------------------------

// Kernel 1a: partial[seg][d] = sum_{h in seg} v[h] * W[h, H+d]
// 128 blocks (32 seg x 4 d-blocks); 32 coalesced 1KB row-reads per block.
__global__ __launch_bounds__(256) void ue_partial_kernel(const float* __restrict__ W,
                                                         const float* __restrict__ v,
                                                         float* __restrict__ partial) {
    const int seg  = blockIdx.x >> 2;          // 0..31
    const int dblk = blockIdx.x & 3;           // 0..3
    const int d    = dblk * 256 + threadIdx.x; // 0..1023
    const int h0   = seg * (H / NSEG);         // 32 h per segment

    float acc = 0.f;
    #pragma unroll
    for (int i = 0; i < H / NSEG; ++i) {
        const int h = h0 + i;
        acc = fmaf(v[h], W[(size_t)h * (2 * H) + H + d], acc);
    }
    partial[seg * H + d] = acc;
}

// Kernel 1b: ue[d] = sum_seg partial[seg][d]   — 4 blocks, trivial.
__global__ __launch_bounds__(256) void ue_reduce_kernel(const float* __restrict__ partial,
                                                        float* __restrict__ ue) {
    const int d = blockIdx.x * 256 + threadIdx.x;
    float acc = 0.f;
    #pragma unroll
    for (int seg = 0; seg < NSEG; ++seg)
        acc += partial[seg * H + d];
    ue[d] = acc;
}

// ---------------------------------------------------------------------------
// Kernel 2: energy[row] = dot(enc[row, :], ue)   for row in [0, B*S)
// One wave per row; 4x float4 loads per lane (row = 4 KB). Reads the full
// 268 MB encoder tensor once — the memory-bound floor of the whole op.
// ---------------------------------------------------------------------------
__global__ __launch_bounds__(256) void energy_kernel(const float* __restrict__ enc,
                                                     const float* __restrict__ ue,
                                                     float* __restrict__ energy) {
    const int wave = threadIdx.x >> 6;              // 0..3
    const int lane = threadIdx.x & 63;
    const int row  = blockIdx.x * 4 + wave;         // 0..B*S-1

    const float4* __restrict__ erow = reinterpret_cast<const float4*>(enc) + (size_t)row * (H / 4);
    const float4* __restrict__ u4   = reinterpret_cast<const float4*>(ue);

    float acc = 0.f;
    #pragma unroll
    for (int it = 0; it < H / 4 / 64; ++it) {       // 4 iterations
        const int idx = it * 64 + lane;
        const float4 e = erow[idx];
        const float4 u = u4[idx];
        acc += e.x * u.x + e.y * u.y + e.z * u.z + e.w * u.w;
    }
    #pragma unroll
    for (int off = 32; off > 0; off >>= 1)
        acc += __shfl_xor(acc, off, 64);
    if (lane == 0) energy[row] = acc;
}

// ---------------------------------------------------------------------------
// Kernel 3: out[b, s] = softmax_s(energy[b, :])   — one block per b.
// ---------------------------------------------------------------------------
__global__ __launch_bounds__(256) void softmax_kernel(const float* __restrict__ energy,
                                                      float* __restrict__ out) {
    const int b    = blockIdx.x;
    const int tid  = threadIdx.x;
    const int lane = tid & 63;
    const int wave = tid >> 6;

    const float* __restrict__ e = energy + (size_t)b * S;

    float vals[8];
    float m = -INFINITY;
    #pragma unroll
    for (int i = 0; i < 8; ++i) {
        vals[i] = e[tid + i * 256];
        m = fmaxf(m, vals[i]);
    }
    #pragma unroll
    for (int off = 32; off > 0; off >>= 1)
        m = fmaxf(m, __shfl_xor(m, off, 64));

    __shared__ float wred[4];
    if (lane == 0) wred[wave] = m;
    __syncthreads();
    m = fmaxf(fmaxf(wred[0], wred[1]), fmaxf(wred[2], wred[3]));
    __syncthreads();   // wred reused below

    float sum = 0.f;
    #pragma unroll
    for (int i = 0; i < 8; ++i) {
        vals[i] = expf(vals[i] - m);
        sum += vals[i];
    }
    #pragma unroll
    for (int off = 32; off > 0; off >>= 1)
        sum += __shfl_xor(sum, off, 64);
    if (lane == 0) wred[wave] = sum;
    __syncthreads();
    sum = wred[0] + wred[1] + wred[2] + wred[3];

    const float inv = 1.0f / sum;
    #pragma unroll
    for (int i = 0; i < 8; ++i)
        out[(size_t)b * S + tid + i * 256] = vals[i] * inv;
}

// ---------------------------------------------------------------------------
// Workspace layout: [0,4KB)=u_e | [4KB,132KB)=partials | [132KB,388KB)=energy
// ---------------------------------------------------------------------------
extern "C" void kernel_launch(void* const* d_in, const int* in_sizes, int n_in,
                              void* d_out, int out_size, void* d_ws, size_t ws_size,
                              hipStream_t stream) {
    const float* enc = (const float*)d_in[0];
    const float* W   = (const float*)d_in[2];
    const float* v   = (const float*)d_in[4];
    float* out       = (float*)d_out;

    float* ue      = (float*)d_ws;                                 // H floats
    float* partial = ue + H;                                       // NSEG*H floats
    float* energy  = partial + NSEG * H;                           // B*S floats

    ue_partial_kernel<<<NSEG * 4, 256, 0, stream>>>(W, v, partial);
    ue_reduce_kernel<<<H / 256, 256, 0, stream>>>(partial, ue);
    energy_kernel<<<(B * S) / 4, 256, 0, stream>>>(enc, ue, energy);
    softmax_kernel<<<B, 256, 0, stream>>>(energy, out);
}